// Round 1
// baseline (125.691 us; speedup 1.0000x reference)
//
#include <hip/hip_runtime.h>
#include <hip/hip_bf16.h>

// InfAffine: out[b] = 0.1*log1p(1/S_b),  S_b = sum_k w_k * exp(-5*acos(ip_bk)^2)
//   ip = xs @ (mus/||mus||_col),  w_k = exp(-10*alpha_k)
// Strategy: bf16 MFMA GEMM (16x16x32) fused with transcendental epilogue + row
// reduction. Epilogue uses acos(x) = 2*asin(sqrt((1-x)/2)) (valid on [-1,1])
// with a degree-7 Taylor asin — error only grows where terms are ~exp(-30) anyway.

typedef __attribute__((ext_vector_type(8))) short short8;   // 8 bf16 = 4 VGPRs
typedef __attribute__((ext_vector_type(4))) float f32x4;

#define KP 1024   // prototypes (GEMM N)
#define DD 128    // feature dim (GEMM k)

__device__ __forceinline__ unsigned int f2bf(float f) {
  unsigned int u = __float_as_uint(f);
  return (u + 0x7FFFu + ((u >> 16) & 1u)) >> 16;   // RNE fp32->bf16
}

// ---- prep: column norms of mus, normalized bf16 transpose [K][D], w=exp(-10a)
__global__ __launch_bounds__(256) void prep_kernel(
    const float* __restrict__ mus, const float* __restrict__ alphas,
    unsigned short* __restrict__ musbf, float* __restrict__ w) {
  __shared__ float psum[8][32];
  __shared__ float Tt[32][129];
  __shared__ float inv_s[32];
  const int t = threadIdx.x;
  const int k0 = blockIdx.x * 32;
  const int kk = t & 31, g = t >> 5;
  float s = 0.0f;
  for (int i = 0; i < 16; ++i) {
    float v = mus[(g * 16 + i) * KP + k0 + kk];
    s = fmaf(v, v, s);
  }
  psum[g][kk] = s;
  __syncthreads();
  if (t < 32) {
    float tot = 0.0f;
    for (int g2 = 0; g2 < 8; ++g2) tot += psum[g2][t];
    inv_s[t] = rsqrtf(tot);
    w[k0 + t] = __expf(-10.0f * alphas[k0 + t]);
  }
  for (int i = 0; i < 16; ++i) {            // transpose 128x32 tile via LDS
    int e = i * 256 + t;
    Tt[e & 31][e >> 5] = mus[(e >> 5) * KP + k0 + (e & 31)];
  }
  __syncthreads();
  for (int i = 0; i < 8; ++i) {             // coalesced bf16 writes, [K][D]
    int o = i * 256 + t;
    int kx = o >> 6, dp = o & 63;
    float inv = inv_s[kx];
    float a = Tt[kx][2 * dp] * inv;
    float b = Tt[kx][2 * dp + 1] * inv;
    ((unsigned int*)musbf)[(k0 + kx) * (DD / 2) + dp] =
        f2bf(a) | (f2bf(b) << 16);
  }
}

// ---- fused GEMM + acos^2-softmin epilogue
// block = 256 thr (4 waves), BM=128 rows, loops 8 chunks of BN=128 cols.
// LDS: As/Bs 128x128 bf16, XOR-swizzled 16B units (conflict-free, 64KB total
// -> 2 blocks/CU with launch_bounds(256,2)).
__global__ __launch_bounds__(256, 2) void fused_kernel(
    const float* __restrict__ xs, const unsigned short* __restrict__ musbf,
    const float* __restrict__ w, float* __restrict__ out) {
  __shared__ __align__(16) unsigned short As[128 * 128];
  __shared__ __align__(16) unsigned short Bs[128 * 128];
  const int t = threadIdx.x;
  const int wv = t >> 6;           // wave 0..3 -> 32-row stripe
  const int ln = t & 63;
  const int q = ln >> 4;           // quad 0..3
  const int l15 = ln & 15;
  const int row0 = blockIdx.x * 128;

  // stage A: 128 rows x 128 d, fp32->bf16, swizzled
  {
    const float4* xs4 = (const float4*)(xs + (size_t)row0 * DD);
    #pragma unroll
    for (int i = 0; i < 16; ++i) {
      int e = i * 256 + t;
      int r = e >> 5, c = e & 31;        // c: float4 index (8B bf16 out)
      float4 v = xs4[e];
      unsigned int lo = f2bf(v.x) | (f2bf(v.y) << 16);
      unsigned int hi = f2bf(v.z) | (f2bf(v.w) << 16);
      int cu = c >> 1, half = c & 1;
      unsigned int* p = (unsigned int*)&As[(r << 7) + (((cu ^ (r & 7)) << 3)) + (half << 2)];
      p[0] = lo; p[1] = hi;
    }
  }

  float sums[8];
  #pragma unroll
  for (int i = 0; i < 8; ++i) sums[i] = 0.0f;

  const uint4* bsrc = (const uint4*)musbf;   // [K][8] uint4 rows
  const int ar0 = wv * 32 + l15;             // A row for m-tile 0
  const int ar1 = ar0 + 16;                  // m-tile 1

  for (int j = 0; j < 8; ++j) {
    // stage Bs chunk j (bf16, L2-hot), swizzled
    #pragma unroll
    for (int i = 0; i < 8; ++i) {
      int e = i * 256 + t;
      int n = e >> 4, c = e & 15;
      uint4 v = bsrc[j * 2048 + e];
      *(uint4*)&Bs[(n << 7) + ((c ^ (n & 7)) << 3)] = v;
    }
    __syncthreads();

    f32x4 acc[2][8];
    #pragma unroll
    for (int mt = 0; mt < 2; ++mt)
      #pragma unroll
      for (int nt = 0; nt < 8; ++nt)
        acc[mt][nt] = (f32x4){0.f, 0.f, 0.f, 0.f};

    #pragma unroll
    for (int kkk = 0; kkk < 4; ++kkk) {
      int u0 = kkk * 4 + q;    // logical 16B unit within row
      short8 a0 = *(const short8*)&As[(ar0 << 7) + ((u0 ^ (ar0 & 7)) << 3)];
      short8 a1 = *(const short8*)&As[(ar1 << 7) + ((u0 ^ (ar1 & 7)) << 3)];
      #pragma unroll
      for (int nt = 0; nt < 8; ++nt) {
        int br = nt * 16 + l15;
        short8 b = *(const short8*)&Bs[(br << 7) + ((u0 ^ (br & 7)) << 3)];
        acc[0][nt] = __builtin_amdgcn_mfma_f32_16x16x32_bf16(a0, b, acc[0][nt], 0, 0, 0);
        acc[1][nt] = __builtin_amdgcn_mfma_f32_16x16x32_bf16(a1, b, acc[1][nt], 0, 0, 0);
      }
    }
    __syncthreads();   // all waves done reading Bs before next restage

    // epilogue: term = exp(-5*acos(x)^2) * w_n, accumulate per-row
    // acos(x) = 2*asin(u), u = sqrt((1-x)/2); exp arg = -20*asin^2 (exp2: *log2e)
    #pragma unroll
    for (int nt = 0; nt < 8; ++nt) {
      float wn = w[j * 128 + nt * 16 + l15];
      #pragma unroll
      for (int mt = 0; mt < 2; ++mt) {
        #pragma unroll
        for (int r = 0; r < 4; ++r) {
          float x = acc[mt][nt][r];
          float z = fmaxf(fmaf(x, -0.5f, 0.5f), 0.0f);   // (1-x)/2, clip
          float u = __builtin_amdgcn_sqrtf(z);
          float p = fmaf(z, 0.013964844f, 0.017352764f); // asin Taylor c7..c1
          p = fmaf(z, p, 0.022372159f);
          p = fmaf(z, p, 0.030381944f);
          p = fmaf(z, p, 0.044642857f);
          p = fmaf(z, p, 0.075f);
          p = fmaf(z, p, 0.16666667f);
          float a = fmaf(u * z, p, u);                    // asin(u)
          float term = __builtin_amdgcn_exp2f(a * a * -28.853900818f);
          sums[mt * 4 + r] = fmaf(term, wn, sums[mt * 4 + r]);
        }
      }
    }
  }

  // reduce over the 16 lanes sharing a quad (columns), rows = q*4+r (+mt*16)
  #pragma unroll
  for (int s = 1; s < 16; s <<= 1) {
    #pragma unroll
    for (int i = 0; i < 8; ++i) sums[i] += __shfl_xor(sums[i], s, 64);
  }
  if (l15 == 0) {
    #pragma unroll
    for (int mt = 0; mt < 2; ++mt)
      #pragma unroll
      for (int r = 0; r < 4; ++r) {
        int row = row0 + wv * 32 + mt * 16 + q * 4 + r;
        out[row] = 0.1f * log1pf(1.0f / sums[mt * 4 + r]);
      }
  }
}

extern "C" void kernel_launch(void* const* d_in, const int* in_sizes, int n_in,
                              void* d_out, int out_size, void* d_ws, size_t ws_size,
                              hipStream_t stream) {
  const float* xs     = (const float*)d_in[0];   // [65536,128]
  const float* mus    = (const float*)d_in[1];   // [128,1024]
  const float* alphas = (const float*)d_in[2];   // [1024]
  float* out = (float*)d_out;

  unsigned short* musbf = (unsigned short*)d_ws;                 // 256 KB
  float* w = (float*)((char*)d_ws + (size_t)KP * DD * sizeof(unsigned short));

  prep_kernel<<<KP / 32, 256, 0, stream>>>(mus, alphas, musbf, w);
  const int B = in_sizes[0] / DD;                // 65536
  fused_kernel<<<B / 128, 256, 0, stream>>>(xs, musbf, w, out);
}

// Round 2
// 116.547 us; speedup vs baseline: 1.0785x; 1.0785x over previous
//
#include <hip/hip_runtime.h>
#include <hip/hip_bf16.h>

// out[b] = 0.1*log1p(1/S_b),  S_b = sum_k w_k * exp(-5*acos(ip_bk)^2)
// R2: barrier-free main loop. B (128 k x 64 cols) lives in VGPRs per wave;
// loop over row tiles loading pre-swizzled bf16 A fragments (coalesced 16B).
// acos^2(x) = 4*z*G(z), z=(1-x)/2; arg = z*H(z), H = -28.8539*G (deg-5 poly).

typedef __attribute__((ext_vector_type(8))) short short8;   // 8 bf16
typedef __attribute__((ext_vector_type(4))) float f32x4;

#define KP 1024
#define DD 128

__device__ __forceinline__ unsigned int f2bf(float f) {
  unsigned int u = __float_as_uint(f);
  return (u + 0x7FFFu + ((u >> 16) & 1u)) >> 16;   // RNE fp32->bf16
}

// ---- fused prep: blocks [0,32): mus col-normalize -> bf16 [K][D] + w
//                  blocks [32,4128): xs -> bf16 A-fragment layout (+ zero S)
__global__ __launch_bounds__(256) void prep_kernel(
    const float* __restrict__ xs, const float* __restrict__ mus,
    const float* __restrict__ alphas, unsigned short* __restrict__ abf,
    unsigned short* __restrict__ musbf, float* __restrict__ w,
    float* __restrict__ S) {
  const int t = threadIdx.x;
  if (blockIdx.x < 32) {
    __shared__ float psum[8][32];
    __shared__ float Tt[32][129];
    __shared__ float inv_s[32];
    const int k0 = blockIdx.x * 32;
    const int kk = t & 31, gg = t >> 5;
    float s = 0.0f;
    for (int i = 0; i < 16; ++i) {
      float v = mus[(gg * 16 + i) * KP + k0 + kk];
      s = fmaf(v, v, s);
    }
    psum[gg][kk] = s;
    __syncthreads();
    if (t < 32) {
      float tot = 0.0f;
      for (int j = 0; j < 8; ++j) tot += psum[j][t];
      inv_s[t] = rsqrtf(tot);
      w[k0 + t] = __expf(-10.0f * alphas[k0 + t]);
    }
    for (int i = 0; i < 16; ++i) {          // transpose 128x32 tile via LDS
      int e = i * 256 + t;
      Tt[e & 31][e >> 5] = mus[(e >> 5) * KP + k0 + (e & 31)];
    }
    __syncthreads();
    for (int i = 0; i < 8; ++i) {           // coalesced bf16 writes, [K][D]
      int o = i * 256 + t;
      int kx = o >> 6, dp = o & 63;
      float inv = inv_s[kx];
      float a = Tt[kx][2 * dp] * inv;
      float b = Tt[kx][2 * dp + 1] * inv;
      ((unsigned int*)musbf)[(k0 + kx) * (DD / 2) + dp] =
          f2bf(a) | (f2bf(b) << 16);
    }
  } else {
    const int xb = blockIdx.x - 32;
    if (xb < 256) S[xb * 256 + t] = 0.0f;   // zero row accumulators
    // A' unit u (16B = 8 bf16): mtile=u>>8, kkk=(u>>6)&3, ln=u&63
    // holds xs[row = mtile*16 + (ln&15)][col = kkk*32 + (ln>>4)*8 .. +8]
    const int u = xb * 256 + t;
    const int mtile = u >> 8, kkk = (u >> 6) & 3, ln = u & 63;
    const int row = mtile * 16 + (ln & 15), col = kkk * 32 + (ln >> 4) * 8;
    const float4* p = (const float4*)(xs + (size_t)row * DD + col);
    float4 f0 = p[0], f1 = p[1];
    uint4 o;
    o.x = f2bf(f0.x) | (f2bf(f0.y) << 16);
    o.y = f2bf(f0.z) | (f2bf(f0.w) << 16);
    o.z = f2bf(f1.x) | (f2bf(f1.y) << 16);
    o.w = f2bf(f1.z) | (f2bf(f1.w) << 16);
    ((uint4*)abf)[u] = o;
  }
}

// ---- main: 1024 blocks x 256 thr. Block b: colgroup g=(b>>3)&7 (128 cols),
// rowchunk (b&7)+8*(b>>6) (512 rows, 16 iters of 32). XCD swizzle: the 8
// colgroup-blocks of a rowchunk share b%8 -> same XCD L2 slice of abf.
// Wave wv: rows half mt_half=wv>>1 (16 of 32), cols half col_half=wv&1 (64).
__global__ __launch_bounds__(256, 3) void main_kernel(
    const unsigned short* __restrict__ abf,
    const unsigned short* __restrict__ musbf,
    const float* __restrict__ w, float* __restrict__ S) {
  __shared__ float Spart[512];
  const int t = threadIdx.x;
  const int wv = t >> 6, ln = t & 63, q = ln >> 4, l15 = ln & 15;
  const int b = blockIdx.x;
  const int g = (b >> 3) & 7;
  const int rowchunk = (b & 7) + ((b >> 6) << 3);
  const int mt_half = wv >> 1, col_half = wv & 1;
  const int cbase = g * 128 + col_half * 64;

  Spart[t] = 0.0f;
  Spart[t + 256] = 0.0f;
  __syncthreads();

  // B fragments: 4 nt-tiles x 4 k-chunks, register-resident (64 VGPRs)
  short8 bfrag[4][4];
  float wn[4];
  #pragma unroll
  for (int nt = 0; nt < 4; ++nt) {
    const int colr = cbase + nt * 16 + l15;
    wn[nt] = w[colr];
    const unsigned short* bp = musbf + colr * DD + q * 8;
    #pragma unroll
    for (int kkk = 0; kkk < 4; ++kkk)
      bfrag[nt][kkk] = *(const short8*)(bp + kkk * 32);
  }

  const int r0 = rowchunk * 512;
  // A' shorts offset: mtile*2048 + kkk*512 + ln*8 ; mtile advances by 2/iter
  const unsigned short* ap =
      abf + (size_t)(rowchunk * 32 + mt_half) * 2048 + ln * 8;

  for (int it = 0; it < 16; ++it) {
    short8 afr[4];
    #pragma unroll
    for (int kkk = 0; kkk < 4; ++kkk)
      afr[kkk] = *(const short8*)(ap + kkk * 512);

    f32x4 acc[4];
    #pragma unroll
    for (int nt = 0; nt < 4; ++nt) acc[nt] = (f32x4){0.f, 0.f, 0.f, 0.f};
    #pragma unroll
    for (int kkk = 0; kkk < 4; ++kkk)
      #pragma unroll
      for (int nt = 0; nt < 4; ++nt)
        acc[nt] = __builtin_amdgcn_mfma_f32_16x16x32_bf16(
            afr[kkk], bfrag[nt][kkk], acc[nt], 0, 0, 0);

    // epilogue: term = exp2(z*H(z)) * w,  z = (1-x)/2
    float sums[4] = {0.f, 0.f, 0.f, 0.f};
    #pragma unroll
    for (int nt = 0; nt < 4; ++nt) {
      #pragma unroll
      for (int r = 0; r < 4; ++r) {
        float x = acc[nt][r];
        float z = fmaxf(fmaf(x, -0.5f, 0.5f), 0.0f);
        float h = fmaf(z, -3.6067376f, -2.3449500f);   // H = -28.8539*G(z)
        h = fmaf(z, h, -3.2975886f);
        h = fmaf(z, h, -5.1295823f);
        h = fmaf(z, h, -9.6179669f);
        h = fmaf(z, h, -28.8539008f);
        float e = __builtin_amdgcn_exp2f(z * h);
        sums[r] = fmaf(e, wn[nt], sums[r]);
      }
    }
    // reduce over the 16 col-lanes (row = q*4+r), DPP-able strides
    #pragma unroll
    for (int s = 1; s < 16; s <<= 1)
      #pragma unroll
      for (int r = 0; r < 4; ++r) sums[r] += __shfl_xor(sums[r], s, 64);
    if (l15 == 0) {
      const int base = it * 32 + mt_half * 16 + q * 4;
      #pragma unroll
      for (int r = 0; r < 4; ++r) atomicAdd(&Spart[base + r], sums[r]);
    }
    ap += 4096;
  }

  __syncthreads();
  atomicAdd(&S[r0 + t], Spart[t]);
  atomicAdd(&S[r0 + 256 + t], Spart[t + 256]);
}

__global__ __launch_bounds__(256) void finalize_kernel(
    const float* __restrict__ S, float* __restrict__ out) {
  const int i = blockIdx.x * 256 + threadIdx.x;
  out[i] = 0.1f * log1pf(1.0f / S[i]);
}

extern "C" void kernel_launch(void* const* d_in, const int* in_sizes, int n_in,
                              void* d_out, int out_size, void* d_ws, size_t ws_size,
                              hipStream_t stream) {
  const float* xs     = (const float*)d_in[0];   // [65536,128]
  const float* mus    = (const float*)d_in[1];   // [128,1024]
  const float* alphas = (const float*)d_in[2];   // [1024]
  float* out = (float*)d_out;

  char* p = (char*)d_ws;
  unsigned short* abf   = (unsigned short*)p;                    // 16 MiB
  unsigned short* musbf = (unsigned short*)(p + 16777216);       // 256 KiB
  float* w              = (float*)(p + 16777216 + 262144);       // 4 KiB
  float* S              = (float*)(p + 16777216 + 262144 + 4096);// 256 KiB

  const int B = in_sizes[0] / DD;   // 65536
  prep_kernel<<<32 + (B * DD / 8 + 255) / 256, 256, 0, stream>>>(
      xs, mus, alphas, abf, musbf, w, S);
  main_kernel<<<1024, 256, 0, stream>>>(abf, musbf, w, S);
  finalize_kernel<<<B / 256, 256, 0, stream>>>(S, out);
}

// Round 3
// 110.205 us; speedup vs baseline: 1.1405x; 1.0575x over previous
//
#include <hip/hip_runtime.h>
#include <hip/hip_bf16.h>

// out[b] = 0.1*log1p(1/S_b),  S_b = sum_k w_k * exp(-5*acos(ip_bk)^2)
// R3: wave owns 16 fixed rows (A regs, loaded once from xs, fp32->bf16 inline);
// loops 16 col-groups of 64, B double-buffered in LDS with register prefetch.
// sums accumulate in regs across all cols -> ONE reduce + direct out write.

typedef __attribute__((ext_vector_type(8))) short short8;   // 8 bf16
typedef __attribute__((ext_vector_type(4))) float f32x4;

#define KP 1024
#define DD 128

__device__ __forceinline__ unsigned int f2bf(float f) {
  unsigned int u = __float_as_uint(f);
  return (u + 0x7FFFu + ((u >> 16) & 1u)) >> 16;   // RNE fp32->bf16
}

// ---- prep: 32 blocks x 32 cols. Col norms -> inv, w=exp(-10a), and bf16
// normalized prototypes in staged layout: unit(16B) index = cg*1024 + w0*64 + c
// where cg=col>>6, c=col&63, w0=k/8 (k-major 8-element groups per col).
__global__ __launch_bounds__(256) void prep_kernel(
    const float* __restrict__ mus, const float* __restrict__ alphas,
    uint4* __restrict__ musbf_sw, float* __restrict__ w) {
  __shared__ float psum[8][32];
  __shared__ float Tt[32][129];
  __shared__ float inv_s[32];
  const int t = threadIdx.x;
  const int k0 = blockIdx.x * 32;
  const int kk = t & 31, gg = t >> 5;
  float s = 0.0f;
  for (int i = 0; i < 16; ++i) {
    float v = mus[(gg * 16 + i) * KP + k0 + kk];
    s = fmaf(v, v, s);
  }
  psum[gg][kk] = s;
  __syncthreads();
  if (t < 32) {
    float tot = 0.0f;
    for (int j = 0; j < 8; ++j) tot += psum[j][t];
    inv_s[t] = rsqrtf(tot);
    w[k0 + t] = __expf(-10.0f * alphas[k0 + t]);
  }
  for (int i = 0; i < 16; ++i) {            // transpose 128x32 tile via LDS
    int e = i * 256 + t;
    Tt[e & 31][e >> 5] = mus[(e >> 5) * KP + k0 + (e & 31)];
  }
  __syncthreads();
  #pragma unroll
  for (int i = 0; i < 2; ++i) {             // 512 units, coalesced 16B writes
    int u = i * 256 + t;
    int w0 = u >> 5, c32 = u & 31;
    int col = k0 + c32;
    float inv = inv_s[c32];
    uint4 o;
    o.x = f2bf(Tt[c32][w0 * 8 + 0] * inv) | (f2bf(Tt[c32][w0 * 8 + 1] * inv) << 16);
    o.y = f2bf(Tt[c32][w0 * 8 + 2] * inv) | (f2bf(Tt[c32][w0 * 8 + 3] * inv) << 16);
    o.z = f2bf(Tt[c32][w0 * 8 + 4] * inv) | (f2bf(Tt[c32][w0 * 8 + 5] * inv) << 16);
    o.w = f2bf(Tt[c32][w0 * 8 + 6] * inv) | (f2bf(Tt[c32][w0 * 8 + 7] * inv) << 16);
    musbf_sw[((col >> 6) << 10) + (w0 << 6) + (col & 63)] = o;
  }
}

// ---- main: 1024 blocks x 256 thr (4 blocks/CU). Block b: rows b*64..+64,
// wave wv: rows +wv*16 (A regs). Loop cg=0..15 over 64-col groups: B staged
// into LDS dbuf (load(cg+1) -> compute(cg) -> ds_write(cg+1) -> barrier).
__global__ __launch_bounds__(256, 4) void main_kernel(
    const float* __restrict__ xs, const uint4* __restrict__ musbf_sw,
    const float* __restrict__ w, float* __restrict__ out) {
  __shared__ __align__(16) unsigned short Bs[2][8192];   // 2 x 16 KB
  const int t = threadIdx.x;
  const int wv = t >> 6, ln = t & 63, q = ln >> 4, l15 = ln & 15;

  // A fragments: afr[kkk] = xs[row][kkk*32 + q*8 .. +8], row = block*64+wv*16+l15
  const int row = blockIdx.x * 64 + wv * 16 + l15;
  const float4* xs4 = (const float4*)xs;
  const int base4 = row * 32 + q * 2;
  short8 afr[4];
  #pragma unroll
  for (int kkk = 0; kkk < 4; ++kkk) {
    float4 f0 = xs4[base4 + kkk * 8];
    float4 f1 = xs4[base4 + kkk * 8 + 1];
    union { short8 s; uint4 u; } a;
    a.u.x = f2bf(f0.x) | (f2bf(f0.y) << 16);
    a.u.y = f2bf(f0.z) | (f2bf(f0.w) << 16);
    a.u.z = f2bf(f1.x) | (f2bf(f1.y) << 16);
    a.u.w = f2bf(f1.z) | (f2bf(f1.w) << 16);
    afr[kkk] = a.s;
  }

  // prefetch cg0 into buf0
  uint4 v[4];
  #pragma unroll
  for (int i = 0; i < 4; ++i) v[i] = musbf_sw[i * 256 + t];
  #pragma unroll
  for (int i = 0; i < 4; ++i) *(uint4*)&Bs[0][(i * 256 + t) * 8] = v[i];
  __syncthreads();

  float sums[4] = {0.f, 0.f, 0.f, 0.f};

  for (int cg = 0; cg < 16; ++cg) {
    if (cg < 15) {                        // issue next-B loads (overlap compute)
      #pragma unroll
      for (int i = 0; i < 4; ++i)
        v[i] = musbf_sw[(cg + 1) * 1024 + i * 256 + t];
    }
    float wn[4];
    #pragma unroll
    for (int nt = 0; nt < 4; ++nt) wn[nt] = w[cg * 64 + nt * 16 + l15];

    f32x4 acc[4];
    #pragma unroll
    for (int nt = 0; nt < 4; ++nt) acc[nt] = (f32x4){0.f, 0.f, 0.f, 0.f};
    // B frag LDS short-offset: kkk*2048 + q*512 + nt*128 + l15*8
    const unsigned short* bp = &Bs[cg & 1][q * 512 + l15 * 8];
    #pragma unroll
    for (int kkk = 0; kkk < 4; ++kkk)
      #pragma unroll
      for (int nt = 0; nt < 4; ++nt) {
        short8 b = *(const short8*)(bp + kkk * 2048 + nt * 128);
        acc[nt] = __builtin_amdgcn_mfma_f32_16x16x32_bf16(afr[kkk], b, acc[nt], 0, 0, 0);
      }

    // epilogue: term = exp2(z*H(z))*w, z=(1-x)/2, H = -28.8539*acos^2/(4z) poly
    #pragma unroll
    for (int nt = 0; nt < 4; ++nt)
      #pragma unroll
      for (int r = 0; r < 4; ++r) {
        float x = acc[nt][r];
        float z = fmaxf(fmaf(x, -0.5f, 0.5f), 0.0f);
        float h = fmaf(z, -3.6067376f, -2.3449500f);
        h = fmaf(z, h, -3.2975886f);
        h = fmaf(z, h, -5.1295823f);
        h = fmaf(z, h, -9.6179669f);
        h = fmaf(z, h, -28.8539008f);
        float e = __builtin_amdgcn_exp2f(z * h);
        sums[r] = fmaf(e, wn[nt], sums[r]);
      }

    if (cg < 15) {                        // commit prefetch to other buffer
      #pragma unroll
      for (int i = 0; i < 4; ++i)
        *(uint4*)&Bs[(cg + 1) & 1][(i * 256 + t) * 8] = v[i];
      __syncthreads();
    }
  }

  // one reduce over the 16 col-lanes; rows = q*4+r
  #pragma unroll
  for (int s2 = 1; s2 < 16; s2 <<= 1)
    #pragma unroll
    for (int r = 0; r < 4; ++r) sums[r] += __shfl_xor(sums[r], s2, 64);
  if (l15 == 0) {
    #pragma unroll
    for (int r = 0; r < 4; ++r)
      out[blockIdx.x * 64 + wv * 16 + q * 4 + r] = 0.1f * log1pf(1.0f / sums[r]);
  }
}

extern "C" void kernel_launch(void* const* d_in, const int* in_sizes, int n_in,
                              void* d_out, int out_size, void* d_ws, size_t ws_size,
                              hipStream_t stream) {
  const float* xs     = (const float*)d_in[0];   // [65536,128]
  const float* mus    = (const float*)d_in[1];   // [128,1024]
  const float* alphas = (const float*)d_in[2];   // [1024]
  float* out = (float*)d_out;

  uint4* musbf_sw = (uint4*)d_ws;                              // 256 KiB
  float* w = (float*)((char*)d_ws + 16384 * sizeof(uint4));    // 4 KiB

  prep_kernel<<<KP / 32, 256, 0, stream>>>(mus, alphas, musbf_sw, w);
  const int B = in_sizes[0] / DD;   // 65536
  main_kernel<<<B / 64, 256, 0, stream>>>(xs, musbf_sw, w, out);
}